// Round 1
// baseline (422.825 us; speedup 1.0000x reference)
//
#include <hip/hip_runtime.h>

// CapsuleNetwork routing, fully fused, one block per batch.
// B=2048, S=200, D=64, K=4.
//
// Algebraic restructure: hat[b,k,s,:] = emb[b,s,:] @ W_k + b_k is never
// materialized. Routing needs only:
//   logits[k,s] = emb[s]·u[k] + off[k],  u[k] = W_k @ G[k], off[k] = b_k·G[k]
//   v[k]        = e[k] @ W_k + t[k]·b_k, e[k] = sum_s sw[k,s] emb[s]
// where G = running sum of interests (cw telescopes: cw_i = hat·sum_{j<i} i_j).

#define NB 2048
#define NS 200
#define ND 64
#define NK 4
#define EST 204  // embT row stride (mult of 4 for b128 alignment; 204%32=12 -> even b128 banks)

__device__ __forceinline__ float wred64(float v) {
#pragma unroll
  for (int o = 1; o < 64; o <<= 1) v += __shfl_xor(v, o, 64);
  return v;
}

__global__ __launch_bounds__(256, 2) void caps_kernel(
    const float* __restrict__ his, const float* __restrict__ itemeb,
    const int* __restrict__ mask, const float* __restrict__ W,
    const float* __restrict__ bias, float* __restrict__ out) {
  __shared__ float embT[ND][EST];  // 52224 B, emb[b] transposed: embT[c][s]
  __shared__ float ssw[NK][NS];    // routing weights sw[k][s]
  __shared__ float sG[NK][ND];     // G = sum of interests so far
  __shared__ float su[NK][ND];     // u[k] = W_k @ G[k]
  __shared__ float se[NK][ND];     // e[k] = sum_s sw*emb  (reused for interest at end)
  __shared__ float smsk[NS];
  __shared__ float soff[NK];
  __shared__ float satt[NK];
  __shared__ int sidx;

  const int t = threadIdx.x;
  const int w = t >> 6;  // wave id == k in phases A/D/E
  const int l = t & 63;  // lane
  const int b = blockIdx.x;

  // ---- stage emb[b] transposed into LDS (coalesced float4 global reads) ----
  const float4* src = (const float4*)(his + (size_t)b * NS * ND);
  for (int i = t; i < NS * ND / 4; i += 256) {
    float4 v = src[i];
    int flat = i * 4;
    int s = flat >> 6;
    int c = flat & 63;
    embT[c][s] = v.x;
    embT[c + 1][s] = v.y;
    embT[c + 2][s] = v.z;
    embT[c + 3][s] = v.w;
  }
  for (int i = t; i < NS; i += 256) smsk[i] = (mask[b * NS + i] != 0) ? 1.0f : 0.0f;
  sG[w][l] = 0.0f;  // 4x64 == 256 threads exactly
  __syncthreads();

  for (int it = 0; it < 3; ++it) {
    if (it == 0) {
      // cw == 0 -> softmax over K is uniform 0.25, then masked
      for (int idx = t; idx < NK * NS; idx += 256) {
        int s = idx % NS;
        ((float*)ssw)[idx] = 0.25f * smsk[s];
      }
      __syncthreads();
    } else {
      // ---- Phase A: u[k][c] = sum_d W[c, 64k+d] * G[k][d]; off[k] = b_k . G[k]
      {
        const float4* Wrow = (const float4*)(W + l * (NK * ND) + w * ND);
        const float4* Gk = (const float4*)(&sG[w][0]);
        float acc = 0.0f;
#pragma unroll
        for (int d4 = 0; d4 < ND / 4; ++d4) {
          float4 wv = Wrow[d4];
          float4 gv = Gk[d4];
          acc += wv.x * gv.x + wv.y * gv.y + wv.z * gv.z + wv.w * gv.w;
        }
        su[w][l] = acc;
        float ob = wred64(bias[w * ND + l] * sG[w][l]);
        if (l == 0) soff[w] = ob;
      }
      __syncthreads();
      // ---- Phase B: logits[s][k] = emb[s]·u[k] + off[k]; softmax over k; mask
      {
        int k = t & 3;
        int s0 = t >> 2;  // 0..63; covers s = s0 + 64j
        float offk = soff[k];
        float lg0 = offk, lg1 = offk, lg2 = offk, lg3 = offk;
        for (int c4 = 0; c4 < ND / 4; ++c4) {
          float4 uv = *(const float4*)&su[k][c4 * 4];
#pragma unroll
          for (int cc = 0; cc < 4; ++cc) {
            int c = c4 * 4 + cc;
            float um = (cc == 0) ? uv.x : (cc == 1) ? uv.y : (cc == 2) ? uv.z : uv.w;
            lg0 += embT[c][s0] * um;
            lg1 += embT[c][s0 + 64] * um;
            lg2 += embT[c][s0 + 128] * um;
            if (s0 < NS - 192) lg3 += embT[c][s0 + 192] * um;
          }
        }
        float lgs[4] = {lg0, lg1, lg2, lg3};
#pragma unroll
        for (int j = 0; j < 4; ++j) {
          int s = s0 + 64 * j;
          if (s >= NS) break;  // uniform within each 4-lane k-group
          float v = lgs[j];
          float m = fmaxf(v, __shfl_xor(v, 1, 64));
          m = fmaxf(m, __shfl_xor(m, 2, 64));
          float e = expf(v - m);
          float sum = e + __shfl_xor(e, 1, 64);
          sum += __shfl_xor(sum, 2, 64);
          ssw[k][s] = (e / sum) * smsk[s];
        }
      }
      __syncthreads();
    }

    // ---- Phase D: e[k][c] = sum_s sw[k][s] * embT[c][s]; t[k] = sum_s sw
    float acc = 0.0f, ts = 0.0f;
    for (int s4 = 0; s4 < NS; s4 += 4) {
      float4 swv = *(const float4*)&ssw[w][s4];   // broadcast (same addr all lanes)
      float4 ev = *(const float4*)&embT[l][s4];   // b128, even bank spread
      acc += swv.x * ev.x + swv.y * ev.y + swv.z * ev.z + swv.w * ev.w;
      ts += swv.x + swv.y + swv.z + swv.w;
    }
    se[w][l] = acc;  // wave-local row; no barrier needed (intra-wave ordering)

    // ---- Phase E: v[k][d] = e[k]·W[:,64k+d] + t[k]*b[64k+d]; squash
    float accv = ts * bias[w * ND + l];
    for (int c4 = 0; c4 < ND / 4; ++c4) {
      float4 ev = *(const float4*)&se[w][c4 * 4];
      int c = c4 * 4;
      accv += ev.x * W[(c + 0) * (NK * ND) + w * ND + l];  // coalesced 256B/wave
      accv += ev.y * W[(c + 1) * (NK * ND) + w * ND + l];
      accv += ev.z * W[(c + 2) * (NK * ND) + w * ND + l];
      accv += ev.w * W[(c + 3) * (NK * ND) + w * ND + l];
    }
    float n2 = wred64(accv * accv);
    float scale = n2 / (1.0f + n2) / sqrtf(n2 + 1e-9f);
    float inter = scale * accv;

    if (it < 2) {
      sG[w][l] += inter;
      __syncthreads();
    } else {
      // final interest -> out; readout via argmax of interest·item_eb
      out[((size_t)b * NK + w) * ND + l] = inter;
      float dot = wred64(inter * itemeb[b * ND + l]);
      se[w][l] = inter;  // stash for the gather
      if (l == 0) satt[w] = dot;
      __syncthreads();
      if (t == 0) {
        int bi = 0;
        float bv = satt[0];
#pragma unroll
        for (int k = 1; k < NK; ++k)
          if (satt[k] > bv) { bv = satt[k]; bi = k; }  // first-max tiebreak == np.argmax
        sidx = bi;
      }
      __syncthreads();
      if (t < ND) out[(size_t)NB * NK * ND + (size_t)b * ND + t] = se[sidx][t];
    }
  }
}

extern "C" void kernel_launch(void* const* d_in, const int* in_sizes, int n_in,
                              void* d_out, int out_size, void* d_ws, size_t ws_size,
                              hipStream_t stream) {
  (void)in_sizes; (void)n_in; (void)out_size; (void)d_ws; (void)ws_size;
  const float* his = (const float*)d_in[0];
  const float* itemeb = (const float*)d_in[1];
  const int* mask = (const int*)d_in[2];
  const float* W = (const float*)d_in[3];
  const float* bias = (const float*)d_in[4];
  float* out = (float*)d_out;
  caps_kernel<<<NB, 256, 0, stream>>>(his, itemeb, mask, W, bias, out);
}